// Round 5
// baseline (261.990 us; speedup 1.0000x reference)
//
#include <hip/hip_runtime.h>
#include <math.h>

#define DEV __device__ __forceinline__

typedef float v2f __attribute__((ext_vector_type(2)));

DEV float rcp_fast(float x) { return __builtin_amdgcn_rcpf(x); }
DEV float rsq_fast(float x) { return __builtin_amdgcn_rsqf(x); }

// packed upper-triangle index for NxN symmetric, requires i<=j
__host__ __device__ constexpr int TI(int n, int i, int j) {
  return n * i - (i * (i - 1)) / 2 + (j - i);
}

template <int N>
DEV float& sym_at(float (&a)[N * (N + 1) / 2], int i, int j) {
  return (i <= j) ? a[TI(N, i, j)] : a[TI(N, j, i)];
}

// --- branchless rotation params + exact diagonal-block update -------------
template <int N>
DEV void pivot_params(float (&a)[N * (N + 1) / 2], int p, int q,
                      float& c_out, float& s_out) {
  float apq = a[TI(N, p, q)];
  float app = a[TI(N, p, p)];
  float aqq = a[TI(N, q, q)];
  float h = aqq - app;
  float tw = apq + apq;
  float den = fabsf(h) + sqrtf(fmaf(h, h, tw * tw)) + 1e-37f;
  float t = tw * rcp_fast(den);
  t = (h < 0.0f) ? -t : t;
  float c = rsq_fast(fmaf(t, t, 1.0f));
  float s = t * c;
  c_out = c;
  s_out = s;
  a[TI(N, p, p)] = fmaf(-t, apq, app);
  a[TI(N, q, q)] = fmaf( t, apq, aqq);
  a[TI(N, p, q)] = 0.0f;
}

template <int N>
DEV void cross_update(float (&a)[N * (N + 1) / 2], int pa, int qa, int pb,
                      int qb, float ca, float sa, float cb, float sb) {
  float w = sym_at<N>(a, pa, pb), x = sym_at<N>(a, pa, qb);
  float y = sym_at<N>(a, qa, pb), z = sym_at<N>(a, qa, qb);
  float w1 = fmaf(ca, w, -sa * y), x1 = fmaf(ca, x, -sa * z);
  float y1 = fmaf(sa, w,  ca * y), z1 = fmaf(sa, x,  ca * z);
  sym_at<N>(a, pa, pb) = fmaf(cb, w1, -sb * x1);
  sym_at<N>(a, pa, qb) = fmaf(sb, w1,  cb * x1);
  sym_at<N>(a, qa, pb) = fmaf(cb, y1, -sb * z1);
  sym_at<N>(a, qa, qb) = fmaf(sb, y1,  cb * z1);
}

// Parallel-ordering Jacobi 8x8: 7 rounds/sweep, 4 disjoint pivots per round.
template <int SWEEPS>
DEV void pjacobi8(float (&a)[36]) {
  constexpr int P[7][4][2] = {
      {{0, 7}, {1, 6}, {2, 5}, {3, 4}}, {{0, 1}, {2, 7}, {3, 6}, {4, 5}},
      {{0, 2}, {1, 3}, {4, 7}, {5, 6}}, {{0, 3}, {2, 4}, {1, 5}, {6, 7}},
      {{0, 4}, {3, 5}, {2, 6}, {1, 7}}, {{0, 5}, {4, 6}, {3, 7}, {1, 2}},
      {{0, 6}, {5, 7}, {1, 4}, {2, 3}}};
  for (int sw = 0; sw < SWEEPS; ++sw) {
#pragma unroll
    for (int r = 0; r < 7; ++r) {
      float cc[4], ss[4];
#pragma unroll
      for (int u = 0; u < 4; ++u)
        pivot_params<8>(a, P[r][u][0], P[r][u][1], cc[u], ss[u]);
#pragma unroll
      for (int u = 0; u < 4; ++u) {
#pragma unroll
        for (int v = u + 1; v < 4; ++v) {
          cross_update<8>(a, P[r][u][0], P[r][u][1], P[r][v][0], P[r][v][1],
                          cc[u], ss[u], cc[v], ss[v]);
        }
      }
    }
  }
}

// Two independent 4x4 problems in lockstep (2x ILP).
template <int SWEEPS>
DEV void pjacobi4x2(float (&a)[10], float (&b)[10]) {
  constexpr int P[3][2][2] = {
      {{0, 3}, {1, 2}}, {{0, 1}, {2, 3}}, {{0, 2}, {1, 3}}};
  for (int sw = 0; sw < SWEEPS; ++sw) {
#pragma unroll
    for (int r = 0; r < 3; ++r) {
      float ca0, sa0, ca1, sa1, cb0, sb0, cb1, sb1;
      pivot_params<4>(a, P[r][0][0], P[r][0][1], ca0, sa0);
      pivot_params<4>(b, P[r][0][0], P[r][0][1], cb0, sb0);
      pivot_params<4>(a, P[r][1][0], P[r][1][1], ca1, sa1);
      pivot_params<4>(b, P[r][1][0], P[r][1][1], cb1, sb1);
      cross_update<4>(a, P[r][0][0], P[r][0][1], P[r][1][0], P[r][1][1], ca0,
                      sa0, ca1, sa1);
      cross_update<4>(b, P[r][0][0], P[r][0][1], P[r][1][0], P[r][1][1], cb0,
                      sb0, cb1, sb1);
    }
  }
}

// entropy mirroring reference EPS placement
template <int N>
DEV float entropy_of(const float (&a)[N * (N + 1) / 2]) {
  float lam[N];
  float sum = 0.0f;
#pragma unroll
  for (int i = 0; i < N; ++i) {
    float l = fmaxf(a[TI(N, i, i)], 0.0f) + 1e-10f;
    lam[i] = l;
    sum += l;
  }
  float inv = 1.0f / sum;
  float H = 0.0f;
#pragma unroll
  for (int i = 0; i < N; ++i) {
    float p = lam[i] * inv;
    H = fmaf(p, __logf(p + 1e-10f), H);
  }
  return -H;
}

// --- Fused kernel ----------------------------------------------------------
// Block = 256 threads = 4 waves = 4 batches.
// Phase A (all threads): wave w computes batch b's 96 correlation entries
//   (pk_fma + step-0-fused butterfly) and writes them to its LDS row.
// Phase B (threads 0..3): per-batch CC^T -> parallel Jacobi -> entropies.
// LDS rows padded to 100 floats: write is 2-way-free; the 4 float4 readers
// land on distinct banks (100%32=4).
__global__ __launch_bounds__(256) void phiq_fused(
    const float* __restrict__ sites, float* __restrict__ out) {
  __shared__ float lds[4 * 100];
  const int lane = threadIdx.x & 63;
  const int w = threadIdx.x >> 6;
  const int b = blockIdx.x * 4 + w;
  const float4* base = reinterpret_cast<const float4*>(sites) + (size_t)b * 1024;

  v2f lo[16], hi[16];
#pragma unroll
  for (int s = 0; s < 16; ++s) {
    float4 f = base[s * 64 + lane];
    lo[s] = v2f{f.x, f.y};
    hi[s] = v2f{f.z, f.w};
  }

  const int up0 = lane & 1;

  // whole bipartition: 64 entries, butterfly step 0 fused -> wbuf[32]
  float wbuf[32];
#pragma unroll
  for (int m = 0; m < 32; ++m) {
    const int e0 = 2 * m, e1 = 2 * m + 1;
    const int i0 = e0 >> 3, j0 = e0 & 7;
    const int i1 = e1 >> 3, j1 = e1 & 7;
    v2f t0 = __builtin_elementwise_fma(hi[i0], hi[8 + j0], lo[i0] * lo[8 + j0]);
    v2f t1 = __builtin_elementwise_fma(hi[i1], hi[8 + j1], lo[i1] * lo[8 + j1]);
    float p0 = t0.x + t0.y;
    float p1 = t1.x + t1.y;
    float snd = up0 ? p0 : p1;
    float kp  = up0 ? p1 : p0;
    wbuf[m] = kp + __shfl_xor(snd, 1, 64);
  }
#pragma unroll
  for (int d = 1; d < 6; ++d) {
    const int dist = 1 << d;
    const int up = (lane >> d) & 1;
#pragma unroll
    for (int m = 0; m < (64 >> (d + 1)); ++m) {
      float snd = up ? wbuf[2 * m]     : wbuf[2 * m + 1];
      float kp  = up ? wbuf[2 * m + 1] : wbuf[2 * m];
      wbuf[m] = kp + __shfl_xor(snd, dist, 64);
    }
  }
  float cw = wbuf[0];  // C_whole entry `lane` (i*8+j), fully reduced

  // left (entries 0..15) + right (16..31), step-0-fused -> xbuf[16]
  float xbuf[16];
#pragma unroll
  for (int m = 0; m < 16; ++m) {
    const int e0 = 2 * m, e1 = 2 * m + 1;
    const int base_a = (e0 < 16) ? 0 : 8;  // e0,e1 in the same half
    const int ii0 = ((e0 & 15) >> 2), jj0 = (e0 & 3);
    const int ii1 = ((e1 & 15) >> 2), jj1 = (e1 & 3);
    v2f t0 = __builtin_elementwise_fma(hi[base_a + ii0], hi[base_a + 4 + jj0],
                                       lo[base_a + ii0] * lo[base_a + 4 + jj0]);
    v2f t1 = __builtin_elementwise_fma(hi[base_a + ii1], hi[base_a + 4 + jj1],
                                       lo[base_a + ii1] * lo[base_a + 4 + jj1]);
    float p0 = t0.x + t0.y;
    float p1 = t1.x + t1.y;
    float snd = up0 ? p0 : p1;
    float kp  = up0 ? p1 : p0;
    xbuf[m] = kp + __shfl_xor(snd, 1, 64);
  }
#pragma unroll
  for (int d = 1; d < 5; ++d) {
    const int dist = 1 << d;
    const int up = (lane >> d) & 1;
#pragma unroll
    for (int m = 0; m < (32 >> (d + 1)); ++m) {
      float snd = up ? xbuf[2 * m]     : xbuf[2 * m + 1];
      float kp  = up ? xbuf[2 * m + 1] : xbuf[2 * m];
      xbuf[m] = kp + __shfl_xor(snd, dist, 64);
    }
  }
  float clr = xbuf[0] + __shfl_xor(xbuf[0], 32, 64);  // entry (lane&31)

  float* row = lds + w * 100;
  row[lane] = cw;                        // e = 0..63
  if (lane < 32) row[64 + lane] = clr;   // e = 64..95
  __syncthreads();

  if (threadIdx.x >= 4) return;  // waves 1-3 retire; wave 0 keeps 4 lanes

  const int t = threadIdx.x;
  const float4* myrow = reinterpret_cast<const float4*>(lds + t * 100);

  float Cw[64], Cl[16], Cr[16];
#pragma unroll
  for (int j = 0; j < 16; ++j) {
    float4 f = myrow[j];
    Cw[4 * j] = f.x; Cw[4 * j + 1] = f.y; Cw[4 * j + 2] = f.z; Cw[4 * j + 3] = f.w;
  }
#pragma unroll
  for (int j = 0; j < 4; ++j) {
    float4 f = myrow[16 + j];
    Cl[4 * j] = f.x; Cl[4 * j + 1] = f.y; Cl[4 * j + 2] = f.z; Cl[4 * j + 3] = f.w;
    float4 g = myrow[20 + j];
    Cr[4 * j] = g.x; Cr[4 * j + 1] = g.y; Cr[4 * j + 2] = g.z; Cr[4 * j + 3] = g.w;
  }

  float Mw[36];
#pragma unroll
  for (int i = 0; i < 8; ++i) {
#pragma unroll
    for (int j = i; j < 8; ++j) {
      float acc = 0.0f;
#pragma unroll
      for (int k = 0; k < 8; ++k) acc = fmaf(Cw[i * 8 + k], Cw[j * 8 + k], acc);
      Mw[TI(8, i, j)] = acc;
    }
  }
  float Ml[10], Mr[10];
#pragma unroll
  for (int i = 0; i < 4; ++i) {
#pragma unroll
    for (int j = i; j < 4; ++j) {
      float accl = 0.0f, accr = 0.0f;
#pragma unroll
      for (int k = 0; k < 4; ++k) {
        accl = fmaf(Cl[i * 4 + k], Cl[j * 4 + k], accl);
        accr = fmaf(Cr[i * 4 + k], Cr[j * 4 + k], accr);
      }
      Ml[TI(4, i, j)] = accl;
      Mr[TI(4, i, j)] = accr;
    }
  }

  pjacobi8<3>(Mw);
  pjacobi4x2<3>(Ml, Mr);

  float Sw = entropy_of<8>(Mw);
  float Sl = entropy_of<4>(Ml);
  float Sr = entropy_of<4>(Mr);

  out[blockIdx.x * 4 + t] = fmaxf(Sw - Sl - Sr, 0.0f);
}

extern "C" void kernel_launch(void* const* d_in, const int* in_sizes, int n_in,
                              void* d_out, int out_size, void* d_ws, size_t ws_size,
                              hipStream_t stream) {
  const float* sites = (const float*)d_in[0];   // [8192, 16, 256] f32
  float* out = (float*)d_out;                   // [8192] f32
  (void)d_ws; (void)ws_size;

  phiq_fused<<<2048, 256, 0, stream>>>(sites, out);
}

// Round 6
// 201.386 us; speedup vs baseline: 1.3009x; 1.3009x over previous
//
#include <hip/hip_runtime.h>
#include <math.h>

#define DEV __device__ __forceinline__

DEV float rcp_fast(float x) { return __builtin_amdgcn_rcpf(x); }
DEV float rsq_fast(float x) { return __builtin_amdgcn_rsqf(x); }

// packed upper-triangle index for NxN symmetric, requires i<=j
__host__ __device__ constexpr int TI(int n, int i, int j) {
  return n * i - (i * (i - 1)) / 2 + (j - i);
}

template <int N>
DEV float& sym_at(float (&a)[N * (N + 1) / 2], int i, int j) {
  return (i <= j) ? a[TI(N, i, j)] : a[TI(N, j, i)];
}

// --- branchless rotation params + exact diagonal-block update -------------
template <int N>
DEV void pivot_params(float (&a)[N * (N + 1) / 2], int p, int q,
                      float& c_out, float& s_out) {
  float apq = a[TI(N, p, q)];
  float app = a[TI(N, p, p)];
  float aqq = a[TI(N, q, q)];
  float h = aqq - app;
  float tw = apq + apq;
  float den = fabsf(h) + sqrtf(fmaf(h, h, tw * tw)) + 1e-37f;
  float t = tw * rcp_fast(den);
  t = (h < 0.0f) ? -t : t;
  float c = rsq_fast(fmaf(t, t, 1.0f));
  float s = t * c;
  c_out = c;
  s_out = s;
  a[TI(N, p, p)] = fmaf(-t, apq, app);
  a[TI(N, q, q)] = fmaf( t, apq, aqq);
  a[TI(N, p, q)] = 0.0f;
}

template <int N>
DEV void cross_update(float (&a)[N * (N + 1) / 2], int pa, int qa, int pb,
                      int qb, float ca, float sa, float cb, float sb) {
  float w = sym_at<N>(a, pa, pb), x = sym_at<N>(a, pa, qb);
  float y = sym_at<N>(a, qa, pb), z = sym_at<N>(a, qa, qb);
  float w1 = fmaf(ca, w, -sa * y), x1 = fmaf(ca, x, -sa * z);
  float y1 = fmaf(sa, w,  ca * y), z1 = fmaf(sa, x,  ca * z);
  sym_at<N>(a, pa, pb) = fmaf(cb, w1, -sb * x1);
  sym_at<N>(a, pa, qb) = fmaf(sb, w1,  cb * x1);
  sym_at<N>(a, qa, pb) = fmaf(cb, y1, -sb * z1);
  sym_at<N>(a, qa, qb) = fmaf(sb, y1,  cb * z1);
}

// Parallel-ordering Jacobi 8x8: 7 rounds/sweep, 4 disjoint pivots per round.
// 3 sweeps validated in R4: absmax 4.9e-3 vs 2e-2 threshold.
template <int SWEEPS>
DEV void pjacobi8(float (&a)[36]) {
  constexpr int P[7][4][2] = {
      {{0, 7}, {1, 6}, {2, 5}, {3, 4}}, {{0, 1}, {2, 7}, {3, 6}, {4, 5}},
      {{0, 2}, {1, 3}, {4, 7}, {5, 6}}, {{0, 3}, {2, 4}, {1, 5}, {6, 7}},
      {{0, 4}, {3, 5}, {2, 6}, {1, 7}}, {{0, 5}, {4, 6}, {3, 7}, {1, 2}},
      {{0, 6}, {5, 7}, {1, 4}, {2, 3}}};
  for (int sw = 0; sw < SWEEPS; ++sw) {
#pragma unroll
    for (int r = 0; r < 7; ++r) {
      float cc[4], ss[4];
#pragma unroll
      for (int u = 0; u < 4; ++u)
        pivot_params<8>(a, P[r][u][0], P[r][u][1], cc[u], ss[u]);
#pragma unroll
      for (int u = 0; u < 4; ++u) {
#pragma unroll
        for (int v = u + 1; v < 4; ++v) {
          cross_update<8>(a, P[r][u][0], P[r][u][1], P[r][v][0], P[r][v][1],
                          cc[u], ss[u], cc[v], ss[v]);
        }
      }
    }
  }
}

// Two independent 4x4 problems in lockstep (2x ILP).
template <int SWEEPS>
DEV void pjacobi4x2(float (&a)[10], float (&b)[10]) {
  constexpr int P[3][2][2] = {
      {{0, 3}, {1, 2}}, {{0, 1}, {2, 3}}, {{0, 2}, {1, 3}}};
  for (int sw = 0; sw < SWEEPS; ++sw) {
#pragma unroll
    for (int r = 0; r < 3; ++r) {
      float ca0, sa0, ca1, sa1, cb0, sb0, cb1, sb1;
      pivot_params<4>(a, P[r][0][0], P[r][0][1], ca0, sa0);
      pivot_params<4>(b, P[r][0][0], P[r][0][1], cb0, sb0);
      pivot_params<4>(a, P[r][1][0], P[r][1][1], ca1, sa1);
      pivot_params<4>(b, P[r][1][0], P[r][1][1], cb1, sb1);
      cross_update<4>(a, P[r][0][0], P[r][0][1], P[r][1][0], P[r][1][1], ca0,
                      sa0, ca1, sa1);
      cross_update<4>(b, P[r][0][0], P[r][0][1], P[r][1][0], P[r][1][1], cb0,
                      sb0, cb1, sb1);
    }
  }
}

// entropy mirroring reference EPS placement
template <int N>
DEV float entropy_of(const float (&a)[N * (N + 1) / 2]) {
  float lam[N];
  float sum = 0.0f;
#pragma unroll
  for (int i = 0; i < N; ++i) {
    float l = fmaxf(a[TI(N, i, i)], 0.0f) + 1e-10f;
    lam[i] = l;
    sum += l;
  }
  float inv = 1.0f / sum;
  float H = 0.0f;
#pragma unroll
  for (int i = 0; i < N; ++i) {
    float p = lam[i] * inv;
    H = fmaf(p, __logf(p + 1e-10f), H);
  }
  return -H;
}

// --- cross-lane reduction with distribution -------------------------------
DEV float reduce_dist_64(float (&cur)[64], int lane) {
#pragma unroll
  for (int d = 0; d < 6; ++d) {
    const int dist = 1 << d;
    const int up = (lane >> d) & 1;
#pragma unroll
    for (int m = 0; m < (64 >> (d + 1)); ++m) {
      float snd = up ? cur[2 * m]     : cur[2 * m + 1];
      float kp  = up ? cur[2 * m + 1] : cur[2 * m];
      float r = __shfl_xor(snd, dist, 64);
      cur[m] = kp + r;
    }
  }
  return cur[0];
}

DEV float reduce_dist_32(float (&cur)[32], int lane) {
#pragma unroll
  for (int d = 0; d < 5; ++d) {
    const int dist = 1 << d;
    const int up = (lane >> d) & 1;
#pragma unroll
    for (int m = 0; m < (32 >> (d + 1)); ++m) {
      float snd = up ? cur[2 * m]     : cur[2 * m + 1];
      float kp  = up ? cur[2 * m + 1] : cur[2 * m];
      float r = __shfl_xor(snd, dist, 64);
      cur[m] = kp + r;
    }
  }
  float v = cur[0];
  v += __shfl_xor(v, 32, 64);
  return v;
}

// --- Phase 1: correlation matrices (one wave per batch) -------------------
// Layout: cmat[b * 96 + e]  (row per batch -> fully coalesced stores)
//   e in [0,64):  C_whole[i][j], e = i*8+j
//   e in [64,80): C_left;  e in [80,96): C_right
__global__ __launch_bounds__(64) void corr_kernel(
    const float* __restrict__ sites, float* __restrict__ cmat) {
  const int b = blockIdx.x;
  const int lane = threadIdx.x;
  const float4* base = reinterpret_cast<const float4*>(sites) + (size_t)b * 1024;

  float4 v[16];
#pragma unroll
  for (int s = 0; s < 16; ++s) v[s] = base[s * 64 + lane];

  float aw[64];
#pragma unroll
  for (int i = 0; i < 8; ++i) {
#pragma unroll
    for (int j = 0; j < 8; ++j) {
      float4 a = v[i], c = v[8 + j];
      aw[i * 8 + j] =
          fmaf(a.x, c.x, fmaf(a.y, c.y, fmaf(a.z, c.z, a.w * c.w)));
    }
  }
  float cw = reduce_dist_64(aw, lane);

  float alr[32];
#pragma unroll
  for (int i = 0; i < 4; ++i) {
#pragma unroll
    for (int j = 0; j < 4; ++j) {
      float4 a = v[i], c = v[4 + j];
      alr[i * 4 + j] =
          fmaf(a.x, c.x, fmaf(a.y, c.y, fmaf(a.z, c.z, a.w * c.w)));
      float4 a2 = v[8 + i], c2 = v[12 + j];
      alr[16 + i * 4 + j] =
          fmaf(a2.x, c2.x, fmaf(a2.y, c2.y, fmaf(a2.z, c2.z, a2.w * c2.w)));
    }
  }
  float clr = reduce_dist_32(alr, lane);

  float* row = cmat + (size_t)b * 96;
  row[lane] = cw;                        // e = 0..63, contiguous 256B
  if (lane < 32) row[64 + lane] = clr;   // e = 64..95, contiguous 128B
}

// --- Phase 2: eigenvalues + entropies -------------------------------------
// Block = 64 threads = 64 batches, one thread per batch, 64 batches/wave of
// latency amortization. NOTE: keep __launch_bounds__(64) with no min-wave
// arg — lets the compiler take ~256 VGPRs for the ~150-value working set.
// Capping VGPRs (as the fused R5 kernel did at 108) causes scratch spills
// and a 10x slowdown of the Jacobi chain.
__global__ __launch_bounds__(64) void phi_kernel(
    const float* __restrict__ cmat, float* __restrict__ out) {
  __shared__ float4 lds[64 * 25];
  const int t = threadIdx.x;
  const int b0 = blockIdx.x * 64;

  const float4* src = reinterpret_cast<const float4*>(cmat) + (size_t)b0 * 24;
#pragma unroll
  for (int r = 0; r < 24; ++r) {
    int q = r * 64 + t;
    float4 val = src[q];
    int bl = q / 24;
    int e4 = q - bl * 24;
    lds[bl * 25 + e4] = val;
  }
  __syncthreads();

  const float4* myrow = &lds[t * 25];
  float Cw[64], Cl[16], Cr[16];
#pragma unroll
  for (int j = 0; j < 16; ++j) {
    float4 f = myrow[j];
    Cw[4 * j] = f.x; Cw[4 * j + 1] = f.y; Cw[4 * j + 2] = f.z; Cw[4 * j + 3] = f.w;
  }
#pragma unroll
  for (int j = 0; j < 4; ++j) {
    float4 f = myrow[16 + j];
    Cl[4 * j] = f.x; Cl[4 * j + 1] = f.y; Cl[4 * j + 2] = f.z; Cl[4 * j + 3] = f.w;
    float4 g = myrow[20 + j];
    Cr[4 * j] = g.x; Cr[4 * j + 1] = g.y; Cr[4 * j + 2] = g.z; Cr[4 * j + 3] = g.w;
  }

  float Mw[36];
#pragma unroll
  for (int i = 0; i < 8; ++i) {
#pragma unroll
    for (int j = i; j < 8; ++j) {
      float acc = 0.0f;
#pragma unroll
      for (int k = 0; k < 8; ++k) acc = fmaf(Cw[i * 8 + k], Cw[j * 8 + k], acc);
      Mw[TI(8, i, j)] = acc;
    }
  }
  float Ml[10], Mr[10];
#pragma unroll
  for (int i = 0; i < 4; ++i) {
#pragma unroll
    for (int j = i; j < 4; ++j) {
      float accl = 0.0f, accr = 0.0f;
#pragma unroll
      for (int k = 0; k < 4; ++k) {
        accl = fmaf(Cl[i * 4 + k], Cl[j * 4 + k], accl);
        accr = fmaf(Cr[i * 4 + k], Cr[j * 4 + k], accr);
      }
      Ml[TI(4, i, j)] = accl;
      Mr[TI(4, i, j)] = accr;
    }
  }

  pjacobi8<3>(Mw);
  pjacobi4x2<3>(Ml, Mr);

  float Sw = entropy_of<8>(Mw);
  float Sl = entropy_of<4>(Ml);
  float Sr = entropy_of<4>(Mr);

  out[b0 + t] = fmaxf(Sw - Sl - Sr, 0.0f);
}

extern "C" void kernel_launch(void* const* d_in, const int* in_sizes, int n_in,
                              void* d_out, int out_size, void* d_ws, size_t ws_size,
                              hipStream_t stream) {
  const float* sites = (const float*)d_in[0];   // [8192, 16, 256] f32
  float* out = (float*)d_out;                   // [8192] f32
  float* cmat = (float*)d_ws;                   // 8192*96*4 = 3 MiB used

  corr_kernel<<<8192, 64, 0, stream>>>(sites, cmat);
  phi_kernel<<<128, 64, 0, stream>>>(cmat, out);
}